// Round 1
// baseline (1059.742 us; speedup 1.0000x reference)
//
#include <hip/hip_runtime.h>

#define D 30
#define NCLS 5

// ---------------- kernels ----------------

__global__ void k_init_deg(float* deg, int n) {
    int i = blockIdx.x * blockDim.x + threadIdx.x;
    if (i < n) deg[i] = 1.0f;  // self-loop contributes 1
}

__global__ void k_deg_edges(const int* __restrict__ row, float* deg, int e) {
    int i = blockIdx.x * blockDim.x + threadIdx.x;
    if (i < e) atomicAdd(&deg[row[i]], 1.0f);
}

// A[i][d] = emb[x[i]][d] / deg[i]   (pre-scaled h for layer-1 aggregation)
__global__ void k_embed(const int* __restrict__ x, const float* __restrict__ emb,
                        const float* __restrict__ deg, float* __restrict__ A, int n) {
    int tid = blockIdx.x * blockDim.x + threadIdx.x;
    if (tid >= n * D) return;
    int i = tid / D;
    int d = tid - i * D;
    A[tid] = emb[x[i] * D + d] / deg[i];
}

// B = A  (self-loop message: agg init)
__global__ void k_copy(const float* __restrict__ A, float* __restrict__ B, int n) {
    int tid = blockIdx.x * blockDim.x + threadIdx.x;
    if (tid < n * D) B[tid] = A[tid];
}

// B[col[e]][d] += A[row[e]][d]
__global__ void k_scatter(const int* __restrict__ row, const int* __restrict__ col,
                          const float* __restrict__ A, float* __restrict__ B, int e) {
    int tid = blockIdx.x * blockDim.x + threadIdx.x;
    if (tid >= e * D) return;
    int ei = tid / D;
    int d = tid - ei * D;
    atomicAdd(&B[col[ei] * D + d], A[row[ei] * D + d]);
}

// A[i][c] = relu(B[i][:] . W[c][:] + b[c]) * (scale ? 1/deg[i] : 1)
__global__ void k_linear(const float* __restrict__ B, const float* __restrict__ W,
                         const float* __restrict__ b, const float* __restrict__ deg,
                         float* __restrict__ A, int n, int scale) {
    int tid = blockIdx.x * blockDim.x + threadIdx.x;
    if (tid >= n * D) return;
    int i = tid / D;
    int c = tid - i * D;
    const float* brow = B + i * D;
    const float* wrow = W + c * D;
    float acc = b[c];
#pragma unroll
    for (int d = 0; d < D; ++d) acc = fmaf(brow[d], wrow[d], acc);
    acc = fmaxf(acc, 0.0f);
    if (scale) acc /= deg[i];
    A[tid] = acc;
}

// out[i][c] = A[i][:] . Wout[c][:] + bout[c]
__global__ void k_out(const float* __restrict__ A, const float* __restrict__ Wout,
                      const float* __restrict__ bout, float* __restrict__ out, int n) {
    int tid = blockIdx.x * blockDim.x + threadIdx.x;
    if (tid >= n * NCLS) return;
    int i = tid / NCLS;
    int c = tid - i * NCLS;
    const float* arow = A + i * D;
    const float* wrow = Wout + c * D;
    float acc = bout[c];
#pragma unroll
    for (int d = 0; d < D; ++d) acc = fmaf(arow[d], wrow[d], acc);
    out[tid] = acc;
}

// ---------------- launch ----------------

extern "C" void kernel_launch(void* const* d_in, const int* in_sizes, int n_in,
                              void* d_out, int out_size, void* d_ws, size_t ws_size,
                              hipStream_t stream) {
    const int*   x    = (const int*)d_in[0];
    const int*   ei   = (const int*)d_in[1];   // [2, E]: row then col
    const float* emb  = (const float*)d_in[2];
    const float* W1   = (const float*)d_in[3];
    const float* b1   = (const float*)d_in[4];
    const float* W2   = (const float*)d_in[5];
    const float* b2   = (const float*)d_in[6];
    const float* W3   = (const float*)d_in[7];
    const float* b3   = (const float*)d_in[8];
    const float* Wout = (const float*)d_in[9];
    const float* bout = (const float*)d_in[10];
    float* out = (float*)d_out;

    const int N = in_sizes[0];
    const int E = in_sizes[1] / 2;
    const int* row = ei;
    const int* col = ei + E;

    // workspace: deg[N] | A[N*D] | B[N*D]
    float* deg = (float*)d_ws;
    float* A   = deg + N;
    float* B   = A + (size_t)N * D;

    const int BS = 256;
    dim3 blk(BS);
    dim3 gN((N + BS - 1) / BS);
    dim3 gE((E + BS - 1) / BS);
    dim3 gND(((size_t)N * D + BS - 1) / BS);
    dim3 gED(((size_t)E * D + BS - 1) / BS);
    dim3 gNC(((size_t)N * NCLS + BS - 1) / BS);

    // degree (once; row fixed across layers)
    k_init_deg<<<gN, blk, 0, stream>>>(deg, N);
    k_deg_edges<<<gE, blk, 0, stream>>>(row, deg, E);

    // h1_scaled = emb[x] / deg
    k_embed<<<gND, blk, 0, stream>>>(x, emb, deg, A, N);

    const float* Ws[3] = {W1, W2, W3};
    const float* bs[3] = {b1, b2, b3};
    for (int l = 0; l < 3; ++l) {
        k_copy<<<gND, blk, 0, stream>>>(A, B, N);                 // self loops
        k_scatter<<<gED, blk, 0, stream>>>(row, col, A, B, E);    // edge scatter-add
        // layers 0,1 produce pre-scaled features for the next aggregation;
        // layer 2 produces unscaled h3 for the output projection
        k_linear<<<gND, blk, 0, stream>>>(B, Ws[l], bs[l], deg, A, N, l < 2 ? 1 : 0);
    }

    k_out<<<gNC, blk, 0, stream>>>(A, Wout, bout, out, N);
}

// Round 2
// 723.141 us; speedup vs baseline: 1.4655x; 1.4655x over previous
//
#include <hip/hip_runtime.h>

#define D 30
#define NCLS 5

// ---------------- CSR build ----------------

__global__ void k_init_deg(float* deg, int n) {
    int i = blockIdx.x * blockDim.x + threadIdx.x;
    if (i < n) deg[i] = 1.0f;  // self-loop contributes 1
}

// per edge: out-degree (float, for normalization) + in-degree count (int, for CSR)
__global__ void k_count(const int* __restrict__ row, const int* __restrict__ col,
                        float* deg, int* cnt, int e) {
    int i = blockIdx.x * blockDim.x + threadIdx.x;
    if (i < e) {
        atomicAdd(&deg[row[i]], 1.0f);
        atomicAdd(&cnt[col[i]], 1);
    }
}

// scan stage 1: per-block sums of cnt
__global__ void k_scan1(const int* __restrict__ cnt, int* blocksum, int n) {
    __shared__ int s[256];
    int i = blockIdx.x * 256 + threadIdx.x;
    s[threadIdx.x] = (i < n) ? cnt[i] : 0;
    __syncthreads();
    for (int st = 128; st > 0; st >>= 1) {
        if (threadIdx.x < st) s[threadIdx.x] += s[threadIdx.x + st];
        __syncthreads();
    }
    if (threadIdx.x == 0) blocksum[blockIdx.x] = s[0];
}

// scan stage 2: exclusive scan of block sums (nb <= 512), single block of 512
__global__ void k_scan2(int* blocksum, int nb) {
    __shared__ int s[512];
    int v = (threadIdx.x < nb) ? blocksum[threadIdx.x] : 0;
    s[threadIdx.x] = v;
    __syncthreads();
    for (int st = 1; st < 512; st <<= 1) {
        int t = (threadIdx.x >= st) ? s[threadIdx.x - st] : 0;
        __syncthreads();
        s[threadIdx.x] += t;
        __syncthreads();
    }
    if (threadIdx.x < nb) blocksum[threadIdx.x] = s[threadIdx.x] - v;  // exclusive
}

// scan stage 3: per-block exclusive scan + block offset -> off
__global__ void k_scan3(const int* __restrict__ cnt, const int* __restrict__ blocksum,
                        int* off, int n) {
    __shared__ int s[256];
    int i = blockIdx.x * 256 + threadIdx.x;
    int v = (i < n) ? cnt[i] : 0;
    s[threadIdx.x] = v;
    __syncthreads();
    for (int st = 1; st < 256; st <<= 1) {
        int t = (threadIdx.x >= st) ? s[threadIdx.x - st] : 0;
        __syncthreads();
        s[threadIdx.x] += t;
        __syncthreads();
    }
    if (i < n) off[i] = blocksum[blockIdx.x] + s[threadIdx.x] - v;
}

// fill: esrc buckets ordered by destination; cur (=cnt, re-zeroed) is the cursor.
// After this kernel cur[i] == in-degree again (reused by k_aggregate).
__global__ void k_fill(const int* __restrict__ row, const int* __restrict__ col,
                       const int* __restrict__ off, int* cur, int* esrc, int e) {
    int i = blockIdx.x * blockDim.x + threadIdx.x;
    if (i < e) {
        int c = col[i];
        int p = atomicAdd(&cur[c], 1);
        esrc[off[c] + p] = row[i];
    }
}

// ---------------- feature kernels ----------------

// A[i][d] = emb[x[i]][d] / deg[i]   (pre-scaled h for layer-1 aggregation)
__global__ void k_embed(const int* __restrict__ x, const float* __restrict__ emb,
                        const float* __restrict__ deg, float* __restrict__ A, int n) {
    int tid = blockIdx.x * blockDim.x + threadIdx.x;
    if (tid >= n * D) return;
    int i = tid / D;
    int d = tid - i * D;
    A[tid] = emb[x[i] * D + d] / deg[i];
}

// B[i][d] = A[i][d] (self loop) + sum_{k} A[esrc[k]][d]   — no atomics
__global__ void k_aggregate(const float* __restrict__ A, const int* __restrict__ off,
                            const int* __restrict__ cnt, const int* __restrict__ esrc,
                            float* __restrict__ B, int n) {
    int tid = blockIdx.x * blockDim.x + threadIdx.x;
    if (tid >= n * D) return;
    int i = tid / D;
    int d = tid - i * D;
    float acc = A[tid];  // self-loop message (A already scaled by 1/deg)
    int s = off[i];
    int e = s + cnt[i];
    for (int k = s; k < e; ++k) {
        int src = esrc[k];
        acc += A[src * D + d];
    }
    B[tid] = acc;
}

// A[i][c] = relu(B[i][:] . W[c][:] + b[c]) * (scale ? 1/deg[i] : 1)
__global__ void k_linear(const float* __restrict__ B, const float* __restrict__ W,
                         const float* __restrict__ b, const float* __restrict__ deg,
                         float* __restrict__ A, int n, int scale) {
    int tid = blockIdx.x * blockDim.x + threadIdx.x;
    if (tid >= n * D) return;
    int i = tid / D;
    int c = tid - i * D;
    const float* brow = B + i * D;
    const float* wrow = W + c * D;
    float acc = b[c];
#pragma unroll
    for (int d = 0; d < D; ++d) acc = fmaf(brow[d], wrow[d], acc);
    acc = fmaxf(acc, 0.0f);
    if (scale) acc /= deg[i];
    A[tid] = acc;
}

// out[i][c] = A[i][:] . Wout[c][:] + bout[c]
__global__ void k_out(const float* __restrict__ A, const float* __restrict__ Wout,
                      const float* __restrict__ bout, float* __restrict__ out, int n) {
    int tid = blockIdx.x * blockDim.x + threadIdx.x;
    if (tid >= n * NCLS) return;
    int i = tid / NCLS;
    int c = tid - i * NCLS;
    const float* arow = A + i * D;
    const float* wrow = Wout + c * D;
    float acc = bout[c];
#pragma unroll
    for (int d = 0; d < D; ++d) acc = fmaf(arow[d], wrow[d], acc);
    out[tid] = acc;
}

// ---------------- launch ----------------

extern "C" void kernel_launch(void* const* d_in, const int* in_sizes, int n_in,
                              void* d_out, int out_size, void* d_ws, size_t ws_size,
                              hipStream_t stream) {
    const int*   x    = (const int*)d_in[0];
    const int*   ei   = (const int*)d_in[1];   // [2, E]: row then col
    const float* emb  = (const float*)d_in[2];
    const float* W1   = (const float*)d_in[3];
    const float* b1   = (const float*)d_in[4];
    const float* W2   = (const float*)d_in[5];
    const float* b2   = (const float*)d_in[6];
    const float* W3   = (const float*)d_in[7];
    const float* b3   = (const float*)d_in[8];
    const float* Wout = (const float*)d_in[9];
    const float* bout = (const float*)d_in[10];
    float* out = (float*)d_out;

    const int N = in_sizes[0];
    const int E = in_sizes[1] / 2;
    const int* row = ei;
    const int* col = ei + E;

    // workspace layout:
    // deg f32[N] | A f32[N*D] | B f32[N*D] | cnt i32[N] | off i32[N] |
    // blocksum i32[512] | esrc i32[E]                        (~31.6 MB)
    float* deg      = (float*)d_ws;
    float* A        = deg + N;
    float* B        = A + (size_t)N * D;
    int*   cnt      = (int*)(B + (size_t)N * D);
    int*   off      = cnt + N;
    int*   blocksum = off + N;
    int*   esrc     = blocksum + 512;

    const int BS = 256;
    dim3 blk(BS);
    dim3 gN((N + BS - 1) / BS);
    dim3 gE((E + BS - 1) / BS);
    dim3 gND(((size_t)N * D + BS - 1) / BS);
    dim3 gNC(((size_t)N * NCLS + BS - 1) / BS);
    const int nb = (N + BS - 1) / BS;  // 391 <= 512

    // ---- CSR build (once per launch; edges fixed within a call) ----
    hipMemsetAsync(cnt, 0, (size_t)N * sizeof(int), stream);
    k_init_deg<<<gN, blk, 0, stream>>>(deg, N);
    k_count<<<gE, blk, 0, stream>>>(row, col, deg, cnt, E);
    k_scan1<<<dim3(nb), blk, 0, stream>>>(cnt, blocksum, N);
    k_scan2<<<dim3(1), dim3(512), 0, stream>>>(blocksum, nb);
    k_scan3<<<dim3(nb), blk, 0, stream>>>(cnt, blocksum, off, N);
    hipMemsetAsync(cnt, 0, (size_t)N * sizeof(int), stream);  // reuse as cursor
    k_fill<<<gE, blk, 0, stream>>>(row, col, off, cnt, esrc, E);
    // cnt now holds in-degree again

    // ---- features ----
    k_embed<<<gND, blk, 0, stream>>>(x, emb, deg, A, N);

    const float* Ws[3] = {W1, W2, W3};
    const float* bs[3] = {b1, b2, b3};
    for (int l = 0; l < 3; ++l) {
        k_aggregate<<<gND, blk, 0, stream>>>(A, off, cnt, esrc, B, N);
        // layers 0,1 produce pre-scaled features for the next aggregation;
        // layer 2 produces unscaled h3 for the output projection
        k_linear<<<gND, blk, 0, stream>>>(B, Ws[l], bs[l], deg, A, N, l < 2 ? 1 : 0);
    }

    k_out<<<gNC, blk, 0, stream>>>(A, Wout, bout, out, N);
}